// Round 2
// baseline (1631.147 us; speedup 1.0000x reference)
//
#include <hip/hip_runtime.h>
#include <hip/hip_bf16.h>

// ---------------------------------------------------------------------------
// SpatialSelfAttention: GN(32 groups) -> 1x1 Q/K/V -> softmax(QK^T/sqrt(C)) V
//                       -> 1x1 out proj -> residual.
// B=8, C=512, H=W=64 (N=4096). All matmuls as bf16 MFMA gemm_bt (C = A*B^T).
// Workspace budget: 194 MiB (O1T aliases hnT; softmax P in-place inside S).
// ---------------------------------------------------------------------------

typedef __bf16 bf16_t;
typedef __bf16 bf16x8 __attribute__((ext_vector_type(8)));
typedef __bf16 bf16x4 __attribute__((ext_vector_type(4)));
typedef float  f32x4  __attribute__((ext_vector_type(4)));

#define CDIM 512
#define NSP  4096

typedef __attribute__((address_space(1))) const void* as1_cvp;
typedef __attribute__((address_space(3))) void*       as3_vp;

__device__ __forceinline__ void gload_lds16(const void* g, void* l) {
  __builtin_amdgcn_global_load_lds((as1_cvp)g, (as3_vp)l, 16, 0, 0);
}

// ---------------------------------------------------------------------------
// f32 -> bf16 convert (for weights)
// ---------------------------------------------------------------------------
__global__ __launch_bounds__(256) void f32_to_bf16_k(const float* __restrict__ in,
                                                     bf16_t* __restrict__ out, int n) {
  int i = (blockIdx.x * 256 + threadIdx.x) * 4;
  if (i < n) {
    float4 v = *(const float4*)(in + i);
    bf16x4 o;
    o[0] = (bf16_t)v.x; o[1] = (bf16_t)v.y; o[2] = (bf16_t)v.z; o[3] = (bf16_t)v.w;
    *(bf16x4*)(out + i) = o;
  }
}

// ---------------------------------------------------------------------------
// GroupNorm stats: one block per (b, group); group = contiguous 16*4096 floats
// ---------------------------------------------------------------------------
__global__ __launch_bounds__(256) void gn_stats_k(const float* __restrict__ x,
                                                  float* __restrict__ stats) {
  const int gid = blockIdx.x;  // b*32+g
  const float4* base = (const float4*)(x + (long)gid * 65536);
  float s = 0.f, ss = 0.f;
  for (int i = threadIdx.x; i < 16384; i += 256) {
    float4 t = base[i];
    s  += t.x + t.y + t.z + t.w;
    ss += t.x*t.x + t.y*t.y + t.z*t.z + t.w*t.w;
  }
#pragma unroll
  for (int o = 32; o; o >>= 1) { s += __shfl_xor(s, o); ss += __shfl_xor(ss, o); }
  __shared__ float rs[4], rss[4];
  const int lane = threadIdx.x & 63, wid = threadIdx.x >> 6;
  if (lane == 0) { rs[wid] = s; rss[wid] = ss; }
  __syncthreads();
  if (threadIdx.x == 0) {
    s  = rs[0] + rs[1] + rs[2] + rs[3];
    ss = rss[0] + rss[1] + rss[2] + rss[3];
    float mean = s * (1.f / 65536.f);
    float var  = ss * (1.f / 65536.f) - mean * mean;
    stats[gid]       = mean;
    stats[256 + gid] = rsqrtf(var + 1e-6f);
  }
}

// ---------------------------------------------------------------------------
// GN apply + transpose: x[b,c,n] fp32 -> hnT[b,n,c] bf16 (64x64 LDS tile)
// ---------------------------------------------------------------------------
__global__ __launch_bounds__(256) void gn_apply_k(const float* __restrict__ x,
                                                  const float* __restrict__ stats,
                                                  const float* __restrict__ gw,
                                                  const float* __restrict__ gb,
                                                  bf16_t* __restrict__ hnT) {
  __shared__ float tile[64 * 65];
  const int n0 = blockIdx.x * 64;
  const int c0 = blockIdx.y * 64;
  const int b  = blockIdx.z;
  const int tid = threadIdx.x;

  {
    const int cl = tid >> 2, nq = tid & 3;
    const int c = c0 + cl;
    const int g = c >> 4;
    const float mean = stats[b * 32 + g];
    const float rstd = stats[256 + b * 32 + g];
    const float a  = rstd * gw[c];
    const float bb = gb[c] - mean * a;
    const float4* xr = (const float4*)(x + ((long)b * CDIM + c) * NSP + n0 + nq * 16);
#pragma unroll
    for (int i = 0; i < 4; i++) {
      float4 t = xr[i];
      float* d = &tile[cl * 65 + nq * 16 + i * 4];
      d[0] = t.x * a + bb; d[1] = t.y * a + bb; d[2] = t.z * a + bb; d[3] = t.w * a + bb;
    }
  }
  __syncthreads();
  {
    const int nl = tid >> 2, cq = tid & 3;
    union { bf16_t h[16]; uint4 v[2]; } o;
#pragma unroll
    for (int j = 0; j < 16; j++) o.h[j] = (bf16_t)tile[(cq * 16 + j) * 65 + nl];
    bf16_t* dst = hnT + ((long)b * NSP + n0 + nl) * CDIM + c0 + cq * 16;
    ((uint4*)dst)[0] = o.v[0];
    ((uint4*)dst)[1] = o.v[1];
  }
}

// ---------------------------------------------------------------------------
// gemm_bt: C[m,n] = (sum_k A[m,k]*B[n,k] + bias_row[m] + bias_col[n]) * scale
//                   (+ residual[m,n])
// A: [M,K] bf16 row stride ldA, B: [N,K] bf16 row stride ldB. M,N %128, K %32.
// 256 threads = 4 waves (2x2 of 64x64), 16x16x32 bf16 MFMA, 4x4 acc per wave.
// ---------------------------------------------------------------------------
template <int OUT_BF16>
__global__ __launch_bounds__(256) void gemm_bt_k(
    const bf16_t* __restrict__ A, long sAb, long ldA,
    const bf16_t* __restrict__ B, long sBb, long ldB,
    void* __restrict__ Cout, long sCb,
    int M, int N, int K,
    const float* __restrict__ bias_row,
    const float* __restrict__ bias_col,
    float scale,
    const float* __restrict__ residual, long sRb) {
  __shared__ __align__(16) bf16_t sA[128 * 32];
  __shared__ __align__(16) bf16_t sB[128 * 32];

  const int tid  = threadIdx.x;
  const int lane = tid & 63;
  const int wid  = tid >> 6;
  const int wm = wid >> 1, wn = wid & 1;
  const int b = blockIdx.z;
  const int rowBase = blockIdx.y * 128;
  const int colBase = blockIdx.x * 128;

  const bf16_t* Ab = A + (long)b * sAb + (long)rowBase * ldA;
  const bf16_t* Bb = B + (long)b * sBb + (long)colBase * ldB;

  f32x4 acc[4][4];
#pragma unroll
  for (int i = 0; i < 4; i++)
#pragma unroll
    for (int j = 0; j < 4; j++) acc[i][j] = (f32x4){0.f, 0.f, 0.f, 0.f};

  // staging chunks: q in [0,512), row = q>>2, k-chunk = (q&3)*8 elems, 16B each
  const int q0 = tid, q1 = tid + 256;
  const int r0 = q0 >> 2, k0c = (q0 & 3) * 8;
  const int r1 = q1 >> 2, k1c = (q1 & 3) * 8;

  const int mrow   = lane & 15;
  const int kfrag  = (lane >> 4) * 8;

  for (int kt = 0; kt < K; kt += 32) {
    gload_lds16(Ab + (long)r0 * ldA + kt + k0c, sA + q0 * 8);
    gload_lds16(Ab + (long)r1 * ldA + kt + k1c, sA + q1 * 8);
    gload_lds16(Bb + (long)r0 * ldB + kt + k0c, sB + q0 * 8);
    gload_lds16(Bb + (long)r1 * ldB + kt + k1c, sB + q1 * 8);
    __syncthreads();

    bf16x8 af[4], bfr[4];
#pragma unroll
    for (int t = 0; t < 4; t++) {
      af[t]  = *(const bf16x8*)&sA[(wm * 64 + t * 16 + mrow) * 32 + kfrag];
      bfr[t] = *(const bf16x8*)&sB[(wn * 64 + t * 16 + mrow) * 32 + kfrag];
    }
#pragma unroll
    for (int i = 0; i < 4; i++)
#pragma unroll
      for (int j = 0; j < 4; j++)
        acc[i][j] = __builtin_amdgcn_mfma_f32_16x16x32_bf16(af[i], bfr[j], acc[i][j], 0, 0, 0);
    __syncthreads();
  }

  // epilogue: C/D layout col = lane&15, row = (lane>>4)*4 + reg
  const int quad = lane >> 4;
  const int colf = lane & 15;
  const long cb = (long)b * sCb;
#pragma unroll
  for (int i = 0; i < 4; i++) {
#pragma unroll
    for (int j = 0; j < 4; j++) {
#pragma unroll
      for (int r = 0; r < 4; r++) {
        const int row = rowBase + wm * 64 + i * 16 + quad * 4 + r;
        const int col = colBase + wn * 64 + j * 16 + colf;
        float v = acc[i][j][r];
        if (bias_row) v += bias_row[row];
        if (bias_col) v += bias_col[col];
        v *= scale;
        if (residual) v += residual[(long)b * sRb + (long)row * N + col];
        if (OUT_BF16)
          ((bf16_t*)Cout)[cb + (long)row * N + col] = (bf16_t)v;
        else
          ((float*)Cout)[cb + (long)row * N + col] = v;
      }
    }
  }
}

// ---------------------------------------------------------------------------
// row softmax: S fp32 [4096,4096] -> P bf16 written IN PLACE into the front
// half of each S row (row stride 8192 bf16). One block per row; the block
// reads its entire row into registers before any write, so no overlap hazard.
// ---------------------------------------------------------------------------
__global__ __launch_bounds__(256) void softmax_k(float* __restrict__ S) {
  const int row = blockIdx.x;
  const int tid = threadIdx.x;
  const int lane = tid & 63, wid = tid >> 6;
  const float4* sr = (const float4*)(S + (long)row * NSP);
  float4 v[4];
#pragma unroll
  for (int i = 0; i < 4; i++) v[i] = sr[tid + 256 * i];

  float m = -1e30f;
#pragma unroll
  for (int i = 0; i < 4; i++)
    m = fmaxf(m, fmaxf(fmaxf(v[i].x, v[i].y), fmaxf(v[i].z, v[i].w)));
#pragma unroll
  for (int o = 32; o; o >>= 1) m = fmaxf(m, __shfl_xor(m, o));
  __shared__ float rm[4], rsum[4];
  if (lane == 0) rm[wid] = m;
  __syncthreads();
  m = fmaxf(fmaxf(rm[0], rm[1]), fmaxf(rm[2], rm[3]));

  float s = 0.f;
#pragma unroll
  for (int i = 0; i < 4; i++) {
    v[i].x = __expf(v[i].x - m); v[i].y = __expf(v[i].y - m);
    v[i].z = __expf(v[i].z - m); v[i].w = __expf(v[i].w - m);
    s += v[i].x + v[i].y + v[i].z + v[i].w;
  }
#pragma unroll
  for (int o = 32; o; o >>= 1) s += __shfl_xor(s, o);
  if (lane == 0) rsum[wid] = s;
  __syncthreads();
  s = rsum[0] + rsum[1] + rsum[2] + rsum[3];
  const float inv = 1.f / s;

  // all 16 values of this thread are in registers; block-wide __syncthreads
  // above guarantees every thread finished reading before anyone writes
  __syncthreads();
  bf16_t* pr = (bf16_t*)S + (long)row * 8192;  // in-place, front half of row
#pragma unroll
  for (int i = 0; i < 4; i++) {
    bf16x4 o4;
    o4[0] = (bf16_t)(v[i].x * inv); o4[1] = (bf16_t)(v[i].y * inv);
    o4[2] = (bf16_t)(v[i].z * inv); o4[3] = (bf16_t)(v[i].w * inv);
    *(bf16x4*)(pr + (tid + 256 * i) * 4) = o4;
  }
}

// ---------------------------------------------------------------------------
extern "C" void kernel_launch(void* const* d_in, const int* in_sizes, int n_in,
                              void* d_out, int out_size, void* d_ws, size_t ws_size,
                              hipStream_t stream) {
  const float* x        = (const float*)d_in[0];
  const float* gn_scale = (const float*)d_in[1];
  const float* gn_bias  = (const float*)d_in[2];
  const float* wq = (const float*)d_in[3];
  const float* bq = (const float*)d_in[4];
  const float* wk = (const float*)d_in[5];
  const float* bk = (const float*)d_in[6];
  const float* wv = (const float*)d_in[7];
  const float* bv = (const float*)d_in[8];
  const float* wo = (const float*)d_in[9];
  const float* bo = (const float*)d_in[10];
  float* out = (float*)d_out;

  // ---- workspace layout, total 194 MiB + 2 KiB ----
  const long PB = 2097152;  // per-batch elems of [4096,512] / [512,4096]
  const long MB = 1048576L;
  char* w = (char*)d_ws;
  bf16_t* hnT = (bf16_t*)(w);               //   0..32 MiB  (bf16 [8,4096,512])
  bf16_t* O1T = hnT;                        //   aliases hnT (hnT dead by then)
  bf16_t* QT  = (bf16_t*)(w + 32 * MB);     //  32..64 MiB
  bf16_t* KT  = (bf16_t*)(w + 64 * MB);     //  64..96 MiB
  bf16_t* V   = (bf16_t*)(w + 96 * MB);     //  96..128 MiB
  float*  S   = (float*)(w + 128 * MB);     // 128..192 MiB (per-batch reuse)
  bf16_t* P   = (bf16_t*)S;                 //   in-place, row stride 8192
  bf16_t* wqb = (bf16_t*)(w + 192 * MB);
  bf16_t* wkb = (bf16_t*)(w + 192 * MB + 524288L);
  bf16_t* wvb = (bf16_t*)(w + 192 * MB + 2 * 524288L);
  bf16_t* wob = (bf16_t*)(w + 192 * MB + 3 * 524288L);
  float*  stats = (float*)(w + 192 * MB + 4 * 524288L);  // 512 floats

  const float qscale = 0.044194173824159216f;  // 512^-0.5

  f32_to_bf16_k<<<256, 256, 0, stream>>>(wq, wqb, 262144);
  f32_to_bf16_k<<<256, 256, 0, stream>>>(wk, wkb, 262144);
  f32_to_bf16_k<<<256, 256, 0, stream>>>(wv, wvb, 262144);
  f32_to_bf16_k<<<256, 256, 0, stream>>>(wo, wob, 262144);

  gn_stats_k<<<256, 256, 0, stream>>>(x, stats);
  gn_apply_k<<<dim3(64, 8, 8), 256, 0, stream>>>(x, stats, gn_scale, gn_bias, hnT);

  // QT[b][n,o] = (hnT . wq^T + bq) * scale   -> bf16 [4096,512]
  gemm_bt_k<1><<<dim3(4, 32, 8), 256, 0, stream>>>(
      hnT, PB, 512, wqb, 0, 512, QT, PB, 4096, 512, 512, nullptr, bq, qscale, nullptr, 0);
  // KT[b][n,o] = hnT . wk^T + bk
  gemm_bt_k<1><<<dim3(4, 32, 8), 256, 0, stream>>>(
      hnT, PB, 512, wkb, 0, 512, KT, PB, 4096, 512, 512, nullptr, bk, 1.f, nullptr, 0);
  // V[b][c,n] = wv . hnT^T + bv   -> bf16 [512,4096]
  gemm_bt_k<1><<<dim3(32, 4, 8), 256, 0, stream>>>(
      wvb, 0, 512, hnT, PB, 512, V, PB, 512, 4096, 512, bv, nullptr, 1.f, nullptr, 0);

  for (int b = 0; b < 8; b++) {
    // S[i,j] = QT[b] . KT[b]^T (scale folded into Q), fp32 [4096,4096]
    gemm_bt_k<0><<<dim3(32, 32, 1), 256, 0, stream>>>(
        QT + b * PB, 0, 512, KT + b * PB, 0, 512, S, 0, 4096, 4096, 512,
        nullptr, nullptr, 1.f, nullptr, 0);
    softmax_k<<<4096, 256, 0, stream>>>(S);
    // O1T[b][i,c] = P . V[b]^T  -> bf16 [4096,512]  (O1T aliases hnT; hnT dead)
    gemm_bt_k<1><<<dim3(4, 32, 1), 256, 0, stream>>>(
        P, 0, 8192, V + b * PB, 0, 4096, O1T + b * PB, 0, 4096, 512, 4096,
        nullptr, nullptr, 1.f, nullptr, 0);
  }

  // out[b][c,n] = wo . O1T[b]^T + bo + x   -> fp32 d_out
  gemm_bt_k<0><<<dim3(32, 4, 8), 256, 0, stream>>>(
      wob, 0, 512, O1T, PB, 512, (void*)out, PB, 512, 4096, 512,
      bo, nullptr, 1.f, x, PB);
}

// Round 3
// 1149.979 us; speedup vs baseline: 1.4184x; 1.4184x over previous
//
#include <hip/hip_runtime.h>
#include <hip/hip_bf16.h>

// ---------------------------------------------------------------------------
// SpatialSelfAttention: GN(32) -> 1x1 QKV -> flash attention -> 1x1 out + res.
// B=8, C=512, N=4096. Attention fully fused (no S/P materialization).
// ---------------------------------------------------------------------------

typedef __bf16 bf16_t;
typedef __bf16 bf16x8 __attribute__((ext_vector_type(8)));
typedef __bf16 bf16x4 __attribute__((ext_vector_type(4)));
typedef float  f32x4  __attribute__((ext_vector_type(4)));

#define CDIM 512
#define NSP  4096
#define L2E  1.4426950408889634f

typedef __attribute__((address_space(1))) const void* as1_cvp;
typedef __attribute__((address_space(3))) void*       as3_vp;

__device__ __forceinline__ void gload_lds16(const void* g, void* l) {
  __builtin_amdgcn_global_load_lds((as1_cvp)g, (as3_vp)l, 16, 0, 0);
}

// ---------------------------------------------------------------------------
__global__ __launch_bounds__(256) void f32_to_bf16_k(const float* __restrict__ in,
                                                     bf16_t* __restrict__ out, int n) {
  int i = (blockIdx.x * 256 + threadIdx.x) * 4;
  if (i < n) {
    float4 v = *(const float4*)(in + i);
    bf16x4 o;
    o[0] = (bf16_t)v.x; o[1] = (bf16_t)v.y; o[2] = (bf16_t)v.z; o[3] = (bf16_t)v.w;
    *(bf16x4*)(out + i) = o;
  }
}

// ---------------------------------------------------------------------------
__global__ __launch_bounds__(256) void gn_stats_k(const float* __restrict__ x,
                                                  float* __restrict__ stats) {
  const int gid = blockIdx.x;  // b*32+g
  const float4* base = (const float4*)(x + (long)gid * 65536);
  float s = 0.f, ss = 0.f;
  for (int i = threadIdx.x; i < 16384; i += 256) {
    float4 t = base[i];
    s  += t.x + t.y + t.z + t.w;
    ss += t.x*t.x + t.y*t.y + t.z*t.z + t.w*t.w;
  }
#pragma unroll
  for (int o = 32; o; o >>= 1) { s += __shfl_xor(s, o); ss += __shfl_xor(ss, o); }
  __shared__ float rs[4], rss[4];
  const int lane = threadIdx.x & 63, wid = threadIdx.x >> 6;
  if (lane == 0) { rs[wid] = s; rss[wid] = ss; }
  __syncthreads();
  if (threadIdx.x == 0) {
    s  = rs[0] + rs[1] + rs[2] + rs[3];
    ss = rss[0] + rss[1] + rss[2] + rss[3];
    float mean = s * (1.f / 65536.f);
    float var  = ss * (1.f / 65536.f) - mean * mean;
    stats[gid]       = mean;
    stats[256 + gid] = rsqrtf(var + 1e-6f);
  }
}

// ---------------------------------------------------------------------------
__global__ __launch_bounds__(256) void gn_apply_k(const float* __restrict__ x,
                                                  const float* __restrict__ stats,
                                                  const float* __restrict__ gw,
                                                  const float* __restrict__ gb,
                                                  bf16_t* __restrict__ hnT) {
  __shared__ float tile[64 * 65];
  const int n0 = blockIdx.x * 64;
  const int c0 = blockIdx.y * 64;
  const int b  = blockIdx.z;
  const int tid = threadIdx.x;
  {
    const int cl = tid >> 2, nq = tid & 3;
    const int c = c0 + cl;
    const int g = c >> 4;
    const float mean = stats[b * 32 + g];
    const float rstd = stats[256 + b * 32 + g];
    const float a  = rstd * gw[c];
    const float bb = gb[c] - mean * a;
    const float4* xr = (const float4*)(x + ((long)b * CDIM + c) * NSP + n0 + nq * 16);
#pragma unroll
    for (int i = 0; i < 4; i++) {
      float4 t = xr[i];
      float* d = &tile[cl * 65 + nq * 16 + i * 4];
      d[0] = t.x * a + bb; d[1] = t.y * a + bb; d[2] = t.z * a + bb; d[3] = t.w * a + bb;
    }
  }
  __syncthreads();
  {
    const int nl = tid >> 2, cq = tid & 3;
    union { bf16_t h[16]; uint4 v[2]; } o;
#pragma unroll
    for (int j = 0; j < 16; j++) o.h[j] = (bf16_t)tile[(cq * 16 + j) * 65 + nl];
    bf16_t* dst = hnT + ((long)b * NSP + n0 + nl) * CDIM + c0 + cq * 16;
    ((uint4*)dst)[0] = o.v[0];
    ((uint4*)dst)[1] = o.v[1];
  }
}

// ---------------------------------------------------------------------------
// gemm_bt: C[m,n] = sum_k A[m,k]*B[n,k] (+bias) (*scale) (+residual)
// MODE 0: fp32 out. MODE 1: bf16 out. MODE 2: QK-split epilogue:
//   col<512: Cout  = bf16((v + bias_col[col]) * scale)        (Q, ld 512)
//   col>=512: Cout2 = bf16(v + bias_row[col-512])             (K, ld 512)
// ---------------------------------------------------------------------------
template <int MODE>
__global__ __launch_bounds__(256) void gemm_bt_k(
    const bf16_t* __restrict__ A, long sAb, long ldA,
    const bf16_t* __restrict__ B, long sBb, long ldB,
    void* __restrict__ Cout, long sCb, long ldC, void* __restrict__ Cout2,
    int M, int N, int K,
    const float* __restrict__ bias_row,
    const float* __restrict__ bias_col,
    float scale,
    const float* __restrict__ residual, long sRb) {
  __shared__ __align__(16) bf16_t sA[128 * 32];
  __shared__ __align__(16) bf16_t sB[128 * 32];

  const int tid  = threadIdx.x;
  const int lane = tid & 63;
  const int wid  = tid >> 6;
  const int wm = wid >> 1, wn = wid & 1;
  const int b = blockIdx.z;
  const int rowBase = blockIdx.y * 128;
  const int colBase = blockIdx.x * 128;

  const bf16_t* Ab = A + (long)b * sAb + (long)rowBase * ldA;
  const bf16_t* Bb = B + (long)b * sBb + (long)colBase * ldB;

  f32x4 acc[4][4];
#pragma unroll
  for (int i = 0; i < 4; i++)
#pragma unroll
    for (int j = 0; j < 4; j++) acc[i][j] = (f32x4){0.f, 0.f, 0.f, 0.f};

  const int q0 = tid, q1 = tid + 256;
  const int r0 = q0 >> 2, k0c = (q0 & 3) * 8;
  const int r1 = q1 >> 2, k1c = (q1 & 3) * 8;
  const int mrow  = lane & 15;
  const int kfrag = (lane >> 4) * 8;

  for (int kt = 0; kt < K; kt += 32) {
    gload_lds16(Ab + (long)r0 * ldA + kt + k0c, sA + q0 * 8);
    gload_lds16(Ab + (long)r1 * ldA + kt + k1c, sA + q1 * 8);
    gload_lds16(Bb + (long)r0 * ldB + kt + k0c, sB + q0 * 8);
    gload_lds16(Bb + (long)r1 * ldB + kt + k1c, sB + q1 * 8);
    __syncthreads();
    bf16x8 af[4], bfr[4];
#pragma unroll
    for (int t = 0; t < 4; t++) {
      af[t]  = *(const bf16x8*)&sA[(wm * 64 + t * 16 + mrow) * 32 + kfrag];
      bfr[t] = *(const bf16x8*)&sB[(wn * 64 + t * 16 + mrow) * 32 + kfrag];
    }
#pragma unroll
    for (int i = 0; i < 4; i++)
#pragma unroll
      for (int j = 0; j < 4; j++)
        acc[i][j] = __builtin_amdgcn_mfma_f32_16x16x32_bf16(af[i], bfr[j], acc[i][j], 0, 0, 0);
    __syncthreads();
  }

  const int quad = lane >> 4;
  const int colf = lane & 15;
#pragma unroll
  for (int i = 0; i < 4; i++) {
#pragma unroll
    for (int j = 0; j < 4; j++) {
#pragma unroll
      for (int r = 0; r < 4; r++) {
        const int row = rowBase + wm * 64 + i * 16 + quad * 4 + r;
        const int col = colBase + wn * 64 + j * 16 + colf;
        float v = acc[i][j][r];
        if (MODE == 2) {
          if (col < 512)
            ((bf16_t*)Cout)[(long)b * sCb + (long)row * ldC + col] =
                (bf16_t)((v + bias_col[col]) * scale);
          else
            ((bf16_t*)Cout2)[(long)b * sCb + (long)row * ldC + (col - 512)] =
                (bf16_t)(v + bias_row[col - 512]);
        } else {
          if (bias_row) v += bias_row[row];
          if (bias_col) v += bias_col[col];
          v *= scale;
          if (residual) v += residual[(long)b * sRb + (long)row * ldC + col];
          if (MODE == 1)
            ((bf16_t*)Cout)[(long)b * sCb + (long)row * ldC + col] = (bf16_t)v;
          else
            ((float*)Cout)[(long)b * sCb + (long)row * ldC + col] = v;
        }
      }
    }
  }
}

// ---------------------------------------------------------------------------
// Flash attention: O1T[b][n][c] = softmax_j(QT[n]·KT[j]) · V[:,j]
// Block: 64 Q rows (16/wave), loop 64-key chunks. Q frags persistent in regs,
// O accumulated fp32 in regs, online softmax per quad, P via padded LDS.
// LDS: sK 64x520 bf16 (66560 B, reused for V halves + O epilogue), sP 9216 B.
// ---------------------------------------------------------------------------
__global__ __launch_bounds__(256, 2) void flash_attn_k(
    const bf16_t* __restrict__ QT, const bf16_t* __restrict__ KT,
    const bf16_t* __restrict__ V, bf16_t* __restrict__ O1T) {
  __shared__ __align__(16) bf16_t sK[64 * 520];
  __shared__ __align__(16) bf16_t sP[4][16 * 72];

  const int tid = threadIdx.x, lane = tid & 63, w = tid >> 6;
  const int quad = lane >> 4, l15 = lane & 15;
  const int b = blockIdx.y, q0 = blockIdx.x * 64;

  const bf16_t* Qw = QT + ((long)b * NSP + q0 + w * 16) * CDIM;
  const bf16_t* Kb = KT + (long)b * NSP * CDIM;
  const bf16_t* Vb = V  + (long)b * NSP * CDIM;  // [512][4096]

  // persistent Q fragments: A[m=l15][k = kc*32 + quad*8 .. +7]
  bf16x8 qf[16];
#pragma unroll
  for (int kc = 0; kc < 16; kc++)
    qf[kc] = *(const bf16x8*)(Qw + (long)l15 * CDIM + kc * 32 + quad * 8);

  f32x4 oacc[32];
#pragma unroll
  for (int i = 0; i < 32; i++) oacc[i] = (f32x4){0.f, 0.f, 0.f, 0.f};
  float m_r[4] = {-3e38f, -3e38f, -3e38f, -3e38f};
  float l_r[4] = {0.f, 0.f, 0.f, 0.f};

  for (int j0 = 0; j0 < NSP; j0 += 64) {
    __syncthreads();  // prev iter's V reads done
    // stage K chunk: one row per wave-instruction (1 KB contiguous), pad 8
#pragma unroll
    for (int i = 0; i < 16; i++) {
      const int key = w * 16 + i;
      gload_lds16(Kb + (long)(j0 + key) * CDIM + lane * 8, sK + key * 520 + lane * 8);
    }
    __syncthreads();  // K ready

    // S = Q·K^T  (scale already folded into Q)
    f32x4 sacc[4];
#pragma unroll
    for (int t = 0; t < 4; t++) sacc[t] = (f32x4){0.f, 0.f, 0.f, 0.f};
#pragma unroll
    for (int kc = 0; kc < 16; kc++) {
#pragma unroll
      for (int t = 0; t < 4; t++) {
        bf16x8 kf = *(const bf16x8*)(sK + (t * 16 + l15) * 520 + kc * 32 + quad * 8);
        sacc[t] = __builtin_amdgcn_mfma_f32_16x16x32_bf16(qf[kc], kf, sacc[t], 0, 0, 0);
      }
    }

    // online softmax over this chunk (rows quad*4+r, cols in 16-lane group)
    float alpha[4];
#pragma unroll
    for (int r = 0; r < 4; r++) {
      float mx = fmaxf(fmaxf(sacc[0][r], sacc[1][r]), fmaxf(sacc[2][r], sacc[3][r]));
      mx = fmaxf(mx, __shfl_xor(mx, 1));
      mx = fmaxf(mx, __shfl_xor(mx, 2));
      mx = fmaxf(mx, __shfl_xor(mx, 4));
      mx = fmaxf(mx, __shfl_xor(mx, 8));
      const float mn = fmaxf(m_r[r], mx);
      alpha[r] = exp2f((m_r[r] - mn) * L2E);
      m_r[r] = mn;
      float rs = 0.f;
#pragma unroll
      for (int t = 0; t < 4; t++) {
        const float p = exp2f((sacc[t][r] - mn) * L2E);
        sacc[t][r] = p;
        rs += p;
      }
      rs += __shfl_xor(rs, 1); rs += __shfl_xor(rs, 2);
      rs += __shfl_xor(rs, 4); rs += __shfl_xor(rs, 8);
      l_r[r] = l_r[r] * alpha[r] + rs;
    }
    const f32x4 av = {alpha[0], alpha[1], alpha[2], alpha[3]};
#pragma unroll
    for (int i = 0; i < 32; i++) oacc[i] *= av;

    // P -> LDS (C-layout scatter), then read back as A-frags (same wave)
#pragma unroll
    for (int t = 0; t < 4; t++)
#pragma unroll
      for (int r = 0; r < 4; r++)
        sP[w][(quad * 4 + r) * 72 + t * 16 + l15] = (bf16_t)sacc[t][r];
    const bf16x8 pf0 = *(const bf16x8*)(&sP[w][l15 * 72 + quad * 8]);
    const bf16x8 pf1 = *(const bf16x8*)(&sP[w][l15 * 72 + 32 + quad * 8]);

    // O += P·V, V staged in two 256-channel halves over sK, padded [c][72]
#pragma unroll
    for (int h = 0; h < 2; h++) {
      __syncthreads();  // previous sK readers done
      uint4 tv[8];
#pragma unroll
      for (int i = 0; i < 8; i++) {
        const int g = i * 256 + tid, c = g >> 3, off = g & 7;
        tv[i] = *(const uint4*)(Vb + (long)(h * 256 + c) * NSP + j0 + off * 8);
      }
#pragma unroll
      for (int i = 0; i < 8; i++) {
        const int g = i * 256 + tid, c = g >> 3, off = g & 7;
        *(uint4*)(sK + c * 72 + off * 8) = tv[i];
      }
      __syncthreads();  // V half ready
#pragma unroll
      for (int ct = 0; ct < 16; ct++) {
        const bf16x8 vf0 = *(const bf16x8*)(sK + (ct * 16 + l15) * 72 + quad * 8);
        const bf16x8 vf1 = *(const bf16x8*)(sK + (ct * 16 + l15) * 72 + 32 + quad * 8);
        oacc[h * 16 + ct] =
            __builtin_amdgcn_mfma_f32_16x16x32_bf16(pf0, vf0, oacc[h * 16 + ct], 0, 0, 0);
        oacc[h * 16 + ct] =
            __builtin_amdgcn_mfma_f32_16x16x32_bf16(pf1, vf1, oacc[h * 16 + ct], 0, 0, 0);
      }
    }
  }

  // epilogue: normalize, stage to LDS, coalesced bf16 store
  const f32x4 linv = {1.f / l_r[0], 1.f / l_r[1], 1.f / l_r[2], 1.f / l_r[3]};
  __syncthreads();
#pragma unroll
  for (int ct = 0; ct < 32; ct++) {
    const f32x4 o = oacc[ct] * linv;
#pragma unroll
    for (int r = 0; r < 4; r++)
      sK[(w * 16 + quad * 4 + r) * 520 + ct * 16 + l15] = (bf16_t)o[r];
  }
  __syncthreads();
  bf16_t* Ob = O1T + ((long)b * NSP + q0) * CDIM;
#pragma unroll
  for (int i = 0; i < 16; i++) {
    const int g = i * 256 + tid, row = g >> 6, off = g & 63;
    *(uint4*)(Ob + (long)row * CDIM + off * 8) = *(const uint4*)(sK + row * 520 + off * 8);
  }
}

// ---------------------------------------------------------------------------
extern "C" void kernel_launch(void* const* d_in, const int* in_sizes, int n_in,
                              void* d_out, int out_size, void* d_ws, size_t ws_size,
                              hipStream_t stream) {
  const float* x        = (const float*)d_in[0];
  const float* gn_scale = (const float*)d_in[1];
  const float* gn_bias  = (const float*)d_in[2];
  const float* wq = (const float*)d_in[3];
  const float* bq = (const float*)d_in[4];
  const float* wk = (const float*)d_in[5];
  const float* bk = (const float*)d_in[6];
  const float* wv = (const float*)d_in[7];
  const float* bv = (const float*)d_in[8];
  const float* wo = (const float*)d_in[9];
  const float* bo = (const float*)d_in[10];
  float* out = (float*)d_out;

  // ---- workspace layout, total ~130 MiB ----
  const long PB = 2097152;  // per-batch elems of [4096,512] / [512,4096]
  const long MB = 1048576L;
  char* w = (char*)d_ws;
  bf16_t* hnT  = (bf16_t*)(w);              //   0..32 MiB
  bf16_t* O1T  = hnT;                       //   aliases hnT (dead after projs)
  bf16_t* QT   = (bf16_t*)(w + 32 * MB);    //  32..64
  bf16_t* KT   = (bf16_t*)(w + 64 * MB);    //  64..96
  bf16_t* V    = (bf16_t*)(w + 96 * MB);    //  96..128
  bf16_t* wqkb = (bf16_t*)(w + 128 * MB);   // stacked [1024,512] bf16 (1 MiB)
  bf16_t* wvb  = (bf16_t*)(w + 129 * MB);
  bf16_t* wob  = (bf16_t*)(w + 129 * MB + 524288L);
  float*  stats = (float*)(w + 130 * MB);   // 512 floats

  const float qscale = 0.044194173824159216f;  // 512^-0.5

  f32_to_bf16_k<<<256, 256, 0, stream>>>(wq, wqkb, 262144);
  f32_to_bf16_k<<<256, 256, 0, stream>>>(wk, wqkb + 262144, 262144);
  f32_to_bf16_k<<<256, 256, 0, stream>>>(wv, wvb, 262144);
  f32_to_bf16_k<<<256, 256, 0, stream>>>(wo, wob, 262144);

  gn_stats_k<<<256, 256, 0, stream>>>(x, stats);
  gn_apply_k<<<dim3(64, 8, 8), 256, 0, stream>>>(x, stats, gn_scale, gn_bias, hnT);

  // QT/KT[b][n][c] in one dispatch (stacked weights), scale folded into Q
  gemm_bt_k<2><<<dim3(8, 32, 8), 256, 0, stream>>>(
      hnT, PB, 512, wqkb, 0, 512, QT, PB, 512, KT, 4096, 1024, 512,
      bk, bq, qscale, nullptr, 0);
  // V[b][c][n] = wv . hnT^T + bv
  gemm_bt_k<1><<<dim3(32, 4, 8), 256, 0, stream>>>(
      wvb, 0, 512, hnT, PB, 512, V, PB, 4096, nullptr, 512, 4096, 512,
      bv, nullptr, 1.f, nullptr, 0);

  // fused attention -> O1T[b][n][c]
  flash_attn_k<<<dim3(64, 8), 256, 0, stream>>>(QT, KT, V, O1T);

  // out[b][c][n] = wo . O1T^T + bo + x
  gemm_bt_k<0><<<dim3(32, 4, 8), 256, 0, stream>>>(
      wob, 0, 512, O1T, PB, 512, (void*)out, PB, 4096, nullptr, 512, 4096, 512,
      bo, nullptr, 1.f, x, PB);
}